// Round 7
// baseline (249.310 us; speedup 1.0000x reference)
//
#include <hip/hip_runtime.h>
#include <math.h>

#define B_ 2
#define T_ 50
#define P_ 5111
#define U_ 64

typedef float v2f __attribute__((ext_vector_type(2)));

// quad_perm DPP: dest lane i (within quad) <- src lane sel[i]
#define QPERM(x, ctrl)                                                        \
  __int_as_float(__builtin_amdgcn_mov_dpp(__float_as_int(x), (ctrl), 0xf, 0xf, true))

// ---------------------------------------------------------------------------
// ZX[b,t,k] = sum_d xt[b,t,d] * Wk[d,k],
//   xt[b,t,d] = X[tgt[b,t], d&127] * emb2[cor[b,t], d].  100 blocks.
// ---------------------------------------------------------------------------
__global__ __launch_bounds__(256) void zx_kernel(
    const int* __restrict__ tgt, const int* __restrict__ cor,
    const float* __restrict__ X, const float* __restrict__ emb2,
    const float* __restrict__ Wk, float* __restrict__ ZX) {
  const int bt = blockIdx.x;
  const int k  = threadIdx.x;
  __shared__ float xe[256];
  const int t_ = tgt[bt], c_ = cor[bt];
  xe[k] = X[t_ * 128 + (k & 127)] * emb2[c_ * 256 + k];
  __syncthreads();
  float z = 0.f;
#pragma unroll 8
  for (int d = 0; d < 256; ++d)
    z = fmaf(xe[d], Wk[d * 256 + k], z);
  ZX[bt * 256 + k] = z;
}

// ---------------------------------------------------------------------------
// Fused LSTM (blocks 0,1) + XWT (blocks 2..) kernel.
// LSTM: thread k -> gate g=k&3, unit u=k>>2 (gates of a unit in one quad ->
// DPP gate exchange, no LDS round-trip). h history in LDS, ONE barrier/step.
// ZX rolling register prefetch. G projection in epilogue, off serial path.
// XWT role: XWT[j,p] = b1[j] + sum_{u<128} X[p,u]*W1[64+u,j], 4 p per block;
// runs concurrently with the 2 LSTM blocks on other CUs.
// ---------------------------------------------------------------------------
__global__ __launch_bounds__(256) void lstm_xwt_kernel(
    const float* __restrict__ ZX, const float* __restrict__ Wr,
    const float* __restrict__ bl, const float* __restrict__ W1,
    const float* __restrict__ X, const float* __restrict__ b1,
    float* __restrict__ G, float* __restrict__ XWT) {
  const int blk = blockIdx.x;
  const int k   = threadIdx.x;

  if (blk >= B_) {
    // ---------------- XWT role ----------------
    __shared__ float xrow[4][128];
    const int sub = k >> 6, lane = k & 63;
    const int p = (blk - B_) * 4 + sub;
    if (p < P_) {
      xrow[sub][lane]      = X[p * 128 + lane];
      xrow[sub][64 + lane] = X[p * 128 + 64 + lane];
    }
    __syncthreads();
    if (p < P_ && lane < 50) {
      float acc = b1[lane];
#pragma unroll 16
      for (int u = 0; u < 128; ++u)
        acc = fmaf(xrow[sub][u], W1[(64 + u) * 50 + lane], acc);
      XWT[lane * P_ + p] = acc;
    }
    return;
  }

  // ---------------- LSTM role ----------------
  const int b   = blk;
  const int g   = k & 3;
  const int u   = k >> 2;
  const int col = g * 64 + u;
  __shared__ __align__(16) float H_s[T_ + 1][64];   // H_s[t] = h(t-1)
  __shared__ __align__(16) float W1_s[64 * 50];

  v2f w2[32];
#pragma unroll
  for (int i = 0; i < 32; ++i) {
    v2f t; t.x = Wr[(2 * i) * 256 + col]; t.y = Wr[(2 * i + 1) * 256 + col];
    w2[i] = t;
  }
  const float blv = bl[col];
  float znext = ZX[(b * T_) * 256 + col];
  for (int i = k; i < 64 * 50; i += 256) W1_s[i] = W1[i];
  if (k < 64) H_s[0][k] = 0.f;
  float c = 0.f;
  __syncthreads();

  for (int t = 0; t < T_; ++t) {
    const float zcur = znext;
    if (t + 1 < T_) znext = ZX[(b * T_ + t + 1) * 256 + col];
    const float4* h4 = (const float4*)&H_s[t][0];
    v2f a0 = {0.f, 0.f}, a1 = {0.f, 0.f}, a2 = {0.f, 0.f}, a3 = {0.f, 0.f};
#pragma unroll
    for (int q = 0; q < 16; ++q) {
      const float4 hq = h4[q];
      v2f hlo; hlo.x = hq.x; hlo.y = hq.y;
      v2f hhi; hhi.x = hq.z; hhi.y = hq.w;
      if (q & 1) {
        a2 = __builtin_elementwise_fma(hlo, w2[2 * q], a2);
        a3 = __builtin_elementwise_fma(hhi, w2[2 * q + 1], a3);
      } else {
        a0 = __builtin_elementwise_fma(hlo, w2[2 * q], a0);
        a1 = __builtin_elementwise_fma(hhi, w2[2 * q + 1], a1);
      }
    }
    const v2f as = (a0 + a2) + (a1 + a3);
    const float z = as.x + as.y + zcur + blv;
    const bool isg2 = (g == 2);
    const float arg = isg2 ? (2.f * z) : (-z);
    const float e   = __expf(arg);
    const float v   = __fdividef(1.f, 1.f + e);
    const float res = isg2 ? fmaf(-2.f, v, 1.f) : v;
    const float v1 = QPERM(res, 177);
    const float v2 = QPERM(res, 78);
    const float v3 = QPERM(res, 27);
    const float ig = (g == 0) ? res : (g == 1) ? v1 : (g == 2) ? v2 : v3;
    const float fg = (g == 1) ? res : (g == 0) ? v1 : (g == 3) ? v2 : v3;
    const float gg = (g == 2) ? res : (g == 3) ? v1 : (g == 0) ? v2 : v3;
    const float og = (g == 3) ? res : (g == 2) ? v1 : (g == 1) ? v2 : v3;
    c = fmaf(fg, c, ig * gg);
    const float th = fmaf(-2.f, __fdividef(1.f, 1.f + __expf(2.f * c)), 1.f);
    if (g == 0) H_s[t + 1][u] = og * th;
    __syncthreads();
  }

  // Epilogue (off serial path): G[b,t,:] = H(t)·W1.
  const v2f* W1_2 = (const v2f*)W1_s;
  v2f*       G_2  = (v2f*)G;
  for (int task = k; task < T_ * 25; task += 256) {
    const int t  = task / 25;
    const int jp = task % 25;
    const float* hrow = &H_s[t + 1][0];
    v2f acc = {0.f, 0.f};
#pragma unroll
    for (int u2 = 0; u2 < 64; ++u2) {
      v2f hb; hb.x = hrow[u2]; hb.y = hrow[u2];
      acc = __builtin_elementwise_fma(hb, W1_2[u2 * 25 + jp], acc);
    }
    G_2[b * (T_ * 25) + task] = acc;
  }
}

// ---------------------------------------------------------------------------
// Main fused kernel: thread per (b,p). ALL 50 cosX gather loads issued up
// front into statically-indexed registers (s-loop fully unrolled) so the
// per-step serial chain has no dependent global load. Packed f32 math.
// ---------------------------------------------------------------------------
__global__ __launch_bounds__(256) void out_kernel(
    const int* __restrict__ tgt, const float* __restrict__ cosX,
    const float* __restrict__ G, const float* __restrict__ XWT,
    const float* __restrict__ W2, const float* __restrict__ b2,
    float* __restrict__ out) {
  const int b   = blockIdx.y;
  const int tid = threadIdx.x;
  const int p   = blockIdx.x * 256 + tid;
  __shared__ __align__(16) float G_s[T_ * 50];
  __shared__ __align__(16) float W2_s[50];
  __shared__ int tgt_s[T_];
  for (int i = tid; i < T_ * 50; i += 256) G_s[i] = G[b * T_ * 50 + i];
  if (tid < 50) {
    W2_s[tid]  = W2[tid];
    tgt_s[tid] = tgt[b * T_ + tid];
  }
  __syncthreads();
  if (p >= P_) return;

  float av[T_];
#pragma unroll
  for (int s = 0; s < T_; ++s) av[s] = cosX[tgt_s[s] * P_ + p];

  v2f S2[25];
#pragma unroll
  for (int jj = 0; jj < 25; ++jj) {
    v2f t; t.x = XWT[(2 * jj) * P_ + p]; t.y = XWT[(2 * jj + 1) * P_ + p];
    S2[jj] = t;
  }
  const v2f* W2_2 = (const v2f*)W2_s;
  const float b2v = b2[0];
  const v2f zero2 = {0.f, 0.f};
#pragma unroll
  for (int s = T_ - 1; s >= 0; --s) {
    const v2f* G2 = (const v2f*)&G_s[s * 50];
    v2f av2; av2.x = av[s]; av2.y = av[s];
    v2f acc2; acc2.x = b2v; acc2.y = 0.f;
#pragma unroll
    for (int jj = 0; jj < 25; ++jj) {
      S2[jj] = __builtin_elementwise_fma(av2, G2[jj], S2[jj]);
      const v2f r = __builtin_elementwise_max(S2[jj], zero2);
      acc2 = __builtin_elementwise_fma(r, W2_2[jj], acc2);
    }
    out[(b * T_ + s) * P_ + p] = acc2.x + acc2.y;
  }
}

extern "C" void kernel_launch(void* const* d_in, const int* in_sizes, int n_in,
                              void* d_out, int out_size, void* d_ws, size_t ws_size,
                              hipStream_t stream) {
  const int*   tgt  = (const int*)d_in[0];
  const int*   cor  = (const int*)d_in[1];
  const float* X    = (const float*)d_in[3];
  const float* cosX = (const float*)d_in[4];
  const float* emb2 = (const float*)d_in[6];
  const float* Wk   = (const float*)d_in[7];
  const float* Wr   = (const float*)d_in[8];
  const float* bl   = (const float*)d_in[9];
  const float* W1   = (const float*)d_in[10];
  const float* b1   = (const float*)d_in[11];
  const float* W2   = (const float*)d_in[12];
  const float* b2   = (const float*)d_in[13];
  float* out = (float*)d_out;

  float* ws  = (float*)d_ws;
  float* ZX  = ws;           // 100*256 = 25600 floats
  float* G   = ws + 25600;   // 100*50  =  5000 floats
  float* XWT = ws + 30600;   // 50*5111 = 255550 floats

  const int xw_blocks = (P_ + 3) / 4;  // 1278
  zx_kernel<<<dim3(B_ * T_), dim3(256), 0, stream>>>(tgt, cor, X, emb2, Wk, ZX);
  lstm_xwt_kernel<<<dim3(B_ + xw_blocks), dim3(256), 0, stream>>>(
      ZX, Wr, bl, W1, X, b1, G, XWT);
  out_kernel<<<dim3((P_ + 255) / 256, B_), dim3(256), 0, stream>>>(
      tgt, cosX, G, XWT, W2, b2, out);
}